// Round 5
// baseline (76.229 us; speedup 1.0000x reference)
//
#include <hip/hip_runtime.h>

#define N 512
#define MARGIN 0.2f
#define BLOCK 256
#define NBLOCKS (2 * N)
#define POISON_U32 0xAAAAAAAAu
// Pos sentinel = 2^20: k accumulations (k<=512) and k*2^20 are exact in fp32,
// so sentinel lanes cancel to exactly 0 in (sum - jcnt*si).
#define BIGP 1048576.0f

// ws layout:
//   [0 .. 8191]      : u64-packed float2 per block (mean, valid) — atomicExch targets
//   [16384 + g*256]  : level-1 done counters, g in [0,32), one 256B line each
//   [16384 + 32*256] : level-2 (root) done counter
// All counters start at the harness poison 0xAAAAAAAA (validated in round 3).
// Round 3 lesson: 3072 same-line device atomics serialize (~45us); spreading
// across 33 lines with <=32 adds each makes the tree ~1us.

__global__ __launch_bounds__(BLOCK) void rk_main(const float* __restrict__ scores,
                                                 const int* __restrict__ labels,
                                                 unsigned long long* __restrict__ wsu,
                                                 unsigned int* __restrict__ ctr,
                                                 float* __restrict__ out) {
    __shared__ __align__(16) float pos_s[N];
    __shared__ __align__(16) float neg_s[N];
    __shared__ int cnt_pos, cnt_neg;
    __shared__ float redm[BLOCK / 64], redv[BLOCK / 64];
    __shared__ int sh_last;

    const int b = blockIdx.x;
    const int tid = threadIdx.x;
    const int lane = tid & 63;
    const int wave = tid >> 6;
    const bool colside = (b >= N);
    const int n = colside ? (b - N) : b;

    if (tid == 0) { cnt_pos = 0; cnt_neg = 0; }

    const int m0 = tid, m1 = tid + BLOCK;
    float s0, s1;
    int l0, l1;
    if (!colside) {
        s0 = scores[n * N + m0]; l0 = labels[n * N + m0];
        s1 = scores[n * N + m1]; l1 = labels[n * N + m1];
    } else {
        s0 = scores[m0 * N + n]; l0 = labels[m0 * N + n];
        s1 = scores[m1 * N + n]; l1 = labels[m1 * N + n];
    }
    __syncthreads();  // cnt init visible before wave atomics

    // Ballot compaction: one LDS atomic per wave.
    const unsigned long long mp0 = __ballot(l0 == 1);
    const unsigned long long mp1 = __ballot(l1 == 1);
    const unsigned long long below = (1ull << lane) - 1ull;
    const int cp0 = __popcll(mp0), cp1 = __popcll(mp1);

    int bp = 0, bn = 0;
    if (lane == 0) {
        bp = atomicAdd(&cnt_pos, cp0 + cp1);
        bn = atomicAdd(&cnt_neg, (64 - cp0) + (64 - cp1));
    }
    bp = __shfl(bp, 0, 64);
    bn = __shfl(bn, 0, 64);

    // Fold margin into negs: term = max(neg', pos) - pos.
    if (l0 == 1) pos_s[bp + __popcll(mp0 & below)] = s0;
    else         neg_s[bn + __popcll(~mp0 & below)] = MARGIN + s0;
    if (l1 == 1) pos_s[bp + cp0 + __popcll(mp1 & below)] = s1;
    else         neg_s[bn + (64 - cp0) + __popcll(~mp1 & below)] = MARGIN + s1;

    __syncthreads();
    const int np = cnt_pos, nn = cnt_neg;
    const int nnp = (nn + 15) & ~15;     // neg padded: float4 x 4 waves
    const int ngroups = (np + 63) >> 6;  // pos padded to 64 only
    for (int i = np + tid; i < (ngroups << 6); i += BLOCK) pos_s[i] = BIGP;
    for (int j = nn + tid; j < nnp; j += BLOCK) neg_s[j] = -__builtin_huge_valf();
    __syncthreads();

    const float4* neg4 = (const float4*)neg_s;
    const int jq4 = nnp >> 4;  // float4s per wave-quarter
    const int jbeg = wave * jq4, jend = jbeg + jq4;
    const float jcntf = (float)(jq4 << 2);

    float tot = 0.0f;
    int g = 0;
    // 4-group sweeps: 16 pairs per ds_read_b128, 2 VALU/pair.
    for (; g + 4 <= ngroups; g += 4) {
        const int base = g << 6;
        const float si0 = pos_s[base + lane];
        const float si1 = pos_s[base + 64 + lane];
        const float si2 = pos_s[base + 128 + lane];
        const float si3 = pos_s[base + 192 + lane];
        float a0 = 0.f, a1 = 0.f, a2 = 0.f, a3 = 0.f;
        for (int jj = jbeg; jj < jend; ++jj) {
            const float4 v = neg4[jj];  // wave-uniform broadcast
            a0 += fmaxf(v.x, si0); a1 += fmaxf(v.x, si1);
            a2 += fmaxf(v.x, si2); a3 += fmaxf(v.x, si3);
            a0 += fmaxf(v.y, si0); a1 += fmaxf(v.y, si1);
            a2 += fmaxf(v.y, si2); a3 += fmaxf(v.y, si3);
            a0 += fmaxf(v.z, si0); a1 += fmaxf(v.z, si1);
            a2 += fmaxf(v.z, si2); a3 += fmaxf(v.z, si3);
            a0 += fmaxf(v.w, si0); a1 += fmaxf(v.w, si1);
            a2 += fmaxf(v.w, si2); a3 += fmaxf(v.w, si3);
        }
        tot += (a0 - jcntf * si0) + (a1 - jcntf * si1) +
               (a2 - jcntf * si2) + (a3 - jcntf * si3);
    }
    // 2-group sweep (2x j-unroll).
    if (g + 2 <= ngroups) {
        const int base = g << 6;
        const float si0 = pos_s[base + lane];
        const float si1 = pos_s[base + 64 + lane];
        float a0 = 0.f, a1 = 0.f;
        int jj = jbeg;
        for (; jj + 1 < jend; jj += 2) {
            const float4 v = neg4[jj];
            const float4 u = neg4[jj + 1];
            a0 += fmaxf(v.x, si0); a1 += fmaxf(v.x, si1);
            a0 += fmaxf(v.y, si0); a1 += fmaxf(v.y, si1);
            a0 += fmaxf(v.z, si0); a1 += fmaxf(v.z, si1);
            a0 += fmaxf(v.w, si0); a1 += fmaxf(v.w, si1);
            a0 += fmaxf(u.x, si0); a1 += fmaxf(u.x, si1);
            a0 += fmaxf(u.y, si0); a1 += fmaxf(u.y, si1);
            a0 += fmaxf(u.z, si0); a1 += fmaxf(u.z, si1);
            a0 += fmaxf(u.w, si0); a1 += fmaxf(u.w, si1);
        }
        if (jj < jend) {
            const float4 v = neg4[jj];
            a0 += fmaxf(v.x, si0); a1 += fmaxf(v.x, si1);
            a0 += fmaxf(v.y, si0); a1 += fmaxf(v.y, si1);
            a0 += fmaxf(v.z, si0); a1 += fmaxf(v.z, si1);
            a0 += fmaxf(v.w, si0); a1 += fmaxf(v.w, si1);
        }
        tot += (a0 - jcntf * si0) + (a1 - jcntf * si1);
        g += 2;
    }
    // 1-group sweep.
    if (g < ngroups) {
        const float si0 = pos_s[(g << 6) + lane];
        float a0 = 0.f, a1 = 0.f;
        int jj = jbeg;
        for (; jj + 1 < jend; jj += 2) {
            const float4 v = neg4[jj];
            const float4 u = neg4[jj + 1];
            a0 += fmaxf(v.x, si0); a1 += fmaxf(v.y, si0);
            a0 += fmaxf(v.z, si0); a1 += fmaxf(v.w, si0);
            a0 += fmaxf(u.x, si0); a1 += fmaxf(u.y, si0);
            a0 += fmaxf(u.z, si0); a1 += fmaxf(u.w, si0);
        }
        if (jj < jend) {
            const float4 v = neg4[jj];
            a0 += fmaxf(v.x, si0); a1 += fmaxf(v.y, si0);
            a0 += fmaxf(v.z, si0); a1 += fmaxf(v.w, si0);
        }
        tot += (a0 + a1) - jcntf * si0;
    }

    for (int off = 32; off > 0; off >>= 1) tot += __shfl_down(tot, off, 64);
    if (lane == 0) redm[wave] = tot;
    __syncthreads();

    if (tid == 0) {
        const float t = redm[0] + redm[1] + redm[2] + redm[3];
        const float cnt = (float)np * (float)nn;
        union { float2 f; unsigned long long u; } pk;
        pk.f.x = (cnt > 0.f) ? t / cnt : 0.f;
        pk.f.y = (cnt > 0.f) ? 1.f : 0.f;
        // Coherent-point write, distinct address per block: no contention.
        atomicExch(&wsu[b], pk.u);
        __threadfence();  // result visible before the done-count
        int last = 0;
        const unsigned int old = atomicAdd(&ctr[(b >> 5) * 64], 1u);
        if (old - POISON_U32 == 31u) {  // last of my 32-block group
            const unsigned int old2 = atomicAdd(&ctr[32 * 64], 1u);
            if (old2 - POISON_U32 == 31u) last = 1;  // last group overall
        }
        sh_last = last;
    }
    __syncthreads();

    if (sh_last) {
        // Finalizer block: coherent RMW readback (round-3-validated path),
        // 4 independent 8B RMWs per thread, pipelined.
        float sm = 0.f, sv = 0.f;
        for (int i = tid; i < NBLOCKS; i += BLOCK) {
            union { float2 f; unsigned long long u; } pk;
            pk.u = atomicAdd(&wsu[i], 0ull);
            sm += pk.f.x;
            sv += pk.f.y;
        }
        for (int off = 32; off > 0; off >>= 1) {
            sm += __shfl_down(sm, off, 64);
            sv += __shfl_down(sv, off, 64);
        }
        if (lane == 0) { redm[wave] = sm; redv[wave] = sv; }
        __syncthreads();
        if (tid == 0) {
            out[0] = (redm[0] + redm[1] + redm[2] + redm[3]) /
                     (redv[0] + redv[1] + redv[2] + redv[3]);
        }
    }
}

extern "C" void kernel_launch(void* const* d_in, const int* in_sizes, int n_in,
                              void* d_out, int out_size, void* d_ws, size_t ws_size,
                              hipStream_t stream) {
    const float* scores = (const float*)d_in[0];
    const int*   labels = (const int*)d_in[1];
    float* out = (float*)d_out;
    unsigned long long* wsu = (unsigned long long*)d_ws;
    unsigned int* ctr = (unsigned int*)((char*)d_ws + 16384);

    rk_main<<<NBLOCKS, BLOCK, 0, stream>>>(scores, labels, wsu, ctr, out);
}

// Round 6
// 67.186 us; speedup vs baseline: 1.1346x; 1.1346x over previous
//
#include <hip/hip_runtime.h>

#define N 512
#define MARGIN 0.2f
#define BLOCK 256
#define NBLOCKS (2 * N)
// Pos sentinel = 2^20: k accumulations (k<=512) and k*2^20 are exact in fp32,
// so sentinel lanes cancel to exactly 0 in (sum - jcnt*si).
#define BIGP 1048576.0f

// Two-kernel structure is deliberate: both fusion attempts regressed —
// round 3 (single-line atomics: +31us serialization), round 5 (counter tree +
// threadfence + atomic readback: +10us). Kernel-boundary release/acquire is
// cheaper than any in-kernel cross-XCD coherence protocol here.
__global__ __launch_bounds__(BLOCK) void rk_main(const float* __restrict__ scores,
                                                 const int* __restrict__ labels,
                                                 float2* __restrict__ ws) {
    __shared__ __align__(16) float pos_s[N];
    __shared__ __align__(16) float neg_s[N];
    __shared__ int cnt_pos, cnt_neg;
    __shared__ float red[BLOCK / 64];

    const int b = blockIdx.x;
    const int tid = threadIdx.x;
    const int lane = tid & 63;
    const int wave = tid >> 6;
    const bool colside = (b >= N);
    const int n = colside ? (b - N) : b;

    if (tid == 0) { cnt_pos = 0; cnt_neg = 0; }

    const int m0 = tid, m1 = tid + BLOCK;
    float s0, s1;
    int l0, l1;
    if (!colside) {
        s0 = scores[n * N + m0]; l0 = labels[n * N + m0];
        s1 = scores[n * N + m1]; l1 = labels[n * N + m1];
    } else {
        s0 = scores[m0 * N + n]; l0 = labels[m0 * N + n];
        s1 = scores[m1 * N + n]; l1 = labels[m1 * N + n];
    }
    __syncthreads();  // cnt init visible before wave atomics

    // Ballot compaction: one LDS atomic per wave.
    const unsigned long long mp0 = __ballot(l0 == 1);
    const unsigned long long mp1 = __ballot(l1 == 1);
    const unsigned long long below = (1ull << lane) - 1ull;
    const int cp0 = __popcll(mp0), cp1 = __popcll(mp1);

    int bp = 0, bn = 0;
    if (lane == 0) {
        bp = atomicAdd(&cnt_pos, cp0 + cp1);
        bn = atomicAdd(&cnt_neg, (64 - cp0) + (64 - cp1));
    }
    bp = __shfl(bp, 0, 64);
    bn = __shfl(bn, 0, 64);

    // Fold margin into negs: term = max(neg', pos) - pos.
    if (l0 == 1) pos_s[bp + __popcll(mp0 & below)] = s0;
    else         neg_s[bn + __popcll(~mp0 & below)] = MARGIN + s0;
    if (l1 == 1) pos_s[bp + cp0 + __popcll(mp1 & below)] = s1;
    else         neg_s[bn + (64 - cp0) + __popcll(~mp1 & below)] = MARGIN + s1;

    __syncthreads();
    const int np = cnt_pos, nn = cnt_neg;
    const int nnp = (nn + 15) & ~15;     // neg padded: float4 x 4 waves
    const int ngroups = (np + 63) >> 6;  // pos padded to 64 only
    for (int i = np + tid; i < (ngroups << 6); i += BLOCK) pos_s[i] = BIGP;
    for (int j = nn + tid; j < nnp; j += BLOCK) neg_s[j] = -__builtin_huge_valf();
    __syncthreads();

    const float4* neg4 = (const float4*)neg_s;
    const int jq4 = nnp >> 4;  // float4s per wave-quarter
    const int jbeg = wave * jq4, jend = jbeg + jq4;
    const float jcntf = (float)(jq4 << 2);

    float tot = 0.0f;
    int g = 0;
    // 4-group sweeps: 16 pairs per ds_read_b128, 2 VALU/pair.
    for (; g + 4 <= ngroups; g += 4) {
        const int base = g << 6;
        const float si0 = pos_s[base + lane];
        const float si1 = pos_s[base + 64 + lane];
        const float si2 = pos_s[base + 128 + lane];
        const float si3 = pos_s[base + 192 + lane];
        float a0 = 0.f, a1 = 0.f, a2 = 0.f, a3 = 0.f;
        for (int jj = jbeg; jj < jend; ++jj) {
            const float4 v = neg4[jj];  // wave-uniform broadcast
            a0 += fmaxf(v.x, si0); a1 += fmaxf(v.x, si1);
            a2 += fmaxf(v.x, si2); a3 += fmaxf(v.x, si3);
            a0 += fmaxf(v.y, si0); a1 += fmaxf(v.y, si1);
            a2 += fmaxf(v.y, si2); a3 += fmaxf(v.y, si3);
            a0 += fmaxf(v.z, si0); a1 += fmaxf(v.z, si1);
            a2 += fmaxf(v.z, si2); a3 += fmaxf(v.z, si3);
            a0 += fmaxf(v.w, si0); a1 += fmaxf(v.w, si1);
            a2 += fmaxf(v.w, si2); a3 += fmaxf(v.w, si3);
        }
        tot += (a0 - jcntf * si0) + (a1 - jcntf * si1) +
               (a2 - jcntf * si2) + (a3 - jcntf * si3);
    }
    // 2-group sweep (2x j-unroll).
    if (g + 2 <= ngroups) {
        const int base = g << 6;
        const float si0 = pos_s[base + lane];
        const float si1 = pos_s[base + 64 + lane];
        float a0 = 0.f, a1 = 0.f;
        int jj = jbeg;
        for (; jj + 1 < jend; jj += 2) {
            const float4 v = neg4[jj];
            const float4 u = neg4[jj + 1];
            a0 += fmaxf(v.x, si0); a1 += fmaxf(v.x, si1);
            a0 += fmaxf(v.y, si0); a1 += fmaxf(v.y, si1);
            a0 += fmaxf(v.z, si0); a1 += fmaxf(v.z, si1);
            a0 += fmaxf(v.w, si0); a1 += fmaxf(v.w, si1);
            a0 += fmaxf(u.x, si0); a1 += fmaxf(u.x, si1);
            a0 += fmaxf(u.y, si0); a1 += fmaxf(u.y, si1);
            a0 += fmaxf(u.z, si0); a1 += fmaxf(u.z, si1);
            a0 += fmaxf(u.w, si0); a1 += fmaxf(u.w, si1);
        }
        if (jj < jend) {
            const float4 v = neg4[jj];
            a0 += fmaxf(v.x, si0); a1 += fmaxf(v.x, si1);
            a0 += fmaxf(v.y, si0); a1 += fmaxf(v.y, si1);
            a0 += fmaxf(v.z, si0); a1 += fmaxf(v.z, si1);
            a0 += fmaxf(v.w, si0); a1 += fmaxf(v.w, si1);
        }
        tot += (a0 - jcntf * si0) + (a1 - jcntf * si1);
        g += 2;
    }
    // 1-group sweep.
    if (g < ngroups) {
        const float si0 = pos_s[(g << 6) + lane];
        float a0 = 0.f, a1 = 0.f;
        int jj = jbeg;
        for (; jj + 1 < jend; jj += 2) {
            const float4 v = neg4[jj];
            const float4 u = neg4[jj + 1];
            a0 += fmaxf(v.x, si0); a1 += fmaxf(v.y, si0);
            a0 += fmaxf(v.z, si0); a1 += fmaxf(v.w, si0);
            a0 += fmaxf(u.x, si0); a1 += fmaxf(u.y, si0);
            a0 += fmaxf(u.z, si0); a1 += fmaxf(u.w, si0);
        }
        if (jj < jend) {
            const float4 v = neg4[jj];
            a0 += fmaxf(v.x, si0); a1 += fmaxf(v.y, si0);
            a0 += fmaxf(v.z, si0); a1 += fmaxf(v.w, si0);
        }
        tot += (a0 + a1) - jcntf * si0;
    }

    for (int off = 32; off > 0; off >>= 1) tot += __shfl_down(tot, off, 64);
    if (lane == 0) red[wave] = tot;
    __syncthreads();

    if (tid == 0) {
        const float t = red[0] + red[1] + red[2] + red[3];
        const float cnt = (float)np * (float)nn;
        float2 r;
        r.x = (cnt > 0.f) ? t / cnt : 0.f;
        r.y = (cnt > 0.f) ? 1.f : 0.f;
        ws[b] = r;
    }
}

// Single wave: no LDS, no __syncthreads, float4 loads (2 slots/lane/iter).
__global__ __launch_bounds__(64) void rk_finalize(const float4* __restrict__ ws4,
                                                  float* __restrict__ out) {
    const int lane = threadIdx.x;
    float sm = 0.f, sv = 0.f;
    // 1024 float2 = 512 float4; 64 lanes -> 8 coalesced iterations.
    for (int i = lane; i < (NBLOCKS / 2); i += 64) {
        const float4 v = ws4[i];
        sm += v.x + v.z;
        sv += v.y + v.w;
    }
    for (int off = 32; off > 0; off >>= 1) {
        sm += __shfl_down(sm, off, 64);
        sv += __shfl_down(sv, off, 64);
    }
    if (lane == 0) out[0] = sm / sv;
}

extern "C" void kernel_launch(void* const* d_in, const int* in_sizes, int n_in,
                              void* d_out, int out_size, void* d_ws, size_t ws_size,
                              hipStream_t stream) {
    const float* scores = (const float*)d_in[0];
    const int*   labels = (const int*)d_in[1];
    float* out = (float*)d_out;
    float2* ws = (float2*)d_ws;

    rk_main<<<NBLOCKS, BLOCK, 0, stream>>>(scores, labels, ws);
    rk_finalize<<<1, 64, 0, stream>>>((const float4*)ws, out);
}

// Round 7
// 65.106 us; speedup vs baseline: 1.1708x; 1.0320x over previous
//
#include <hip/hip_runtime.h>

#define N 512
#define MARGIN 0.2f
#define BLOCK 256
#define NBLOCKS (2 * N)
// Pos sentinel = 2^20: k accumulations (k<=512) and k*2^20 are exact in fp32,
// so sentinel lanes cancel to exactly 0 in (sum - jcnt*si).
#define BIGP 1048576.0f

// Two-kernel structure is deliberate: both fusion attempts regressed —
// round 3 (single-line atomics: +31us serialization), round 5 (counter tree +
// threadfence + atomic readback: +10us). Kernel-boundary release/acquire is
// cheaper than any in-kernel cross-XCD coherence protocol here.
// 256-thread finalize (not single-wave): R6 measured the 1-wave variant at
// +1.2us — within noise but never better; keep the best-measured config (R4).
__global__ __launch_bounds__(BLOCK) void rk_main(const float* __restrict__ scores,
                                                 const int* __restrict__ labels,
                                                 float2* __restrict__ ws) {
    __shared__ __align__(16) float pos_s[N];
    __shared__ __align__(16) float neg_s[N];
    __shared__ int cnt_pos, cnt_neg;
    __shared__ float red[BLOCK / 64];

    const int b = blockIdx.x;
    const int tid = threadIdx.x;
    const int lane = tid & 63;
    const int wave = tid >> 6;
    const bool colside = (b >= N);
    const int n = colside ? (b - N) : b;

    if (tid == 0) { cnt_pos = 0; cnt_neg = 0; }

    const int m0 = tid, m1 = tid + BLOCK;
    float s0, s1;
    int l0, l1;
    if (!colside) {
        s0 = scores[n * N + m0]; l0 = labels[n * N + m0];
        s1 = scores[n * N + m1]; l1 = labels[n * N + m1];
    } else {
        s0 = scores[m0 * N + n]; l0 = labels[m0 * N + n];
        s1 = scores[m1 * N + n]; l1 = labels[m1 * N + n];
    }
    __syncthreads();  // cnt init visible before wave atomics

    // Ballot compaction: one LDS atomic per wave.
    const unsigned long long mp0 = __ballot(l0 == 1);
    const unsigned long long mp1 = __ballot(l1 == 1);
    const unsigned long long below = (1ull << lane) - 1ull;
    const int cp0 = __popcll(mp0), cp1 = __popcll(mp1);

    int bp = 0, bn = 0;
    if (lane == 0) {
        bp = atomicAdd(&cnt_pos, cp0 + cp1);
        bn = atomicAdd(&cnt_neg, (64 - cp0) + (64 - cp1));
    }
    bp = __shfl(bp, 0, 64);
    bn = __shfl(bn, 0, 64);

    // Fold margin into negs: term = max(neg', pos) - pos.
    if (l0 == 1) pos_s[bp + __popcll(mp0 & below)] = s0;
    else         neg_s[bn + __popcll(~mp0 & below)] = MARGIN + s0;
    if (l1 == 1) pos_s[bp + cp0 + __popcll(mp1 & below)] = s1;
    else         neg_s[bn + (64 - cp0) + __popcll(~mp1 & below)] = MARGIN + s1;

    __syncthreads();
    const int np = cnt_pos, nn = cnt_neg;
    const int nnp = (nn + 15) & ~15;     // neg padded: float4 x 4 waves
    const int ngroups = (np + 63) >> 6;  // pos padded to 64 only
    for (int i = np + tid; i < (ngroups << 6); i += BLOCK) pos_s[i] = BIGP;
    for (int j = nn + tid; j < nnp; j += BLOCK) neg_s[j] = -__builtin_huge_valf();
    __syncthreads();

    const float4* neg4 = (const float4*)neg_s;
    const int jq4 = nnp >> 4;  // float4s per wave-quarter
    const int jbeg = wave * jq4, jend = jbeg + jq4;
    const float jcntf = (float)(jq4 << 2);

    float tot = 0.0f;
    int g = 0;
    // 4-group sweeps: 16 pairs per ds_read_b128, 2 VALU/pair.
    for (; g + 4 <= ngroups; g += 4) {
        const int base = g << 6;
        const float si0 = pos_s[base + lane];
        const float si1 = pos_s[base + 64 + lane];
        const float si2 = pos_s[base + 128 + lane];
        const float si3 = pos_s[base + 192 + lane];
        float a0 = 0.f, a1 = 0.f, a2 = 0.f, a3 = 0.f;
        for (int jj = jbeg; jj < jend; ++jj) {
            const float4 v = neg4[jj];  // wave-uniform broadcast
            a0 += fmaxf(v.x, si0); a1 += fmaxf(v.x, si1);
            a2 += fmaxf(v.x, si2); a3 += fmaxf(v.x, si3);
            a0 += fmaxf(v.y, si0); a1 += fmaxf(v.y, si1);
            a2 += fmaxf(v.y, si2); a3 += fmaxf(v.y, si3);
            a0 += fmaxf(v.z, si0); a1 += fmaxf(v.z, si1);
            a2 += fmaxf(v.z, si2); a3 += fmaxf(v.z, si3);
            a0 += fmaxf(v.w, si0); a1 += fmaxf(v.w, si1);
            a2 += fmaxf(v.w, si2); a3 += fmaxf(v.w, si3);
        }
        tot += (a0 - jcntf * si0) + (a1 - jcntf * si1) +
               (a2 - jcntf * si2) + (a3 - jcntf * si3);
    }
    // 2-group sweep (2x j-unroll).
    if (g + 2 <= ngroups) {
        const int base = g << 6;
        const float si0 = pos_s[base + lane];
        const float si1 = pos_s[base + 64 + lane];
        float a0 = 0.f, a1 = 0.f;
        int jj = jbeg;
        for (; jj + 1 < jend; jj += 2) {
            const float4 v = neg4[jj];
            const float4 u = neg4[jj + 1];
            a0 += fmaxf(v.x, si0); a1 += fmaxf(v.x, si1);
            a0 += fmaxf(v.y, si0); a1 += fmaxf(v.y, si1);
            a0 += fmaxf(v.z, si0); a1 += fmaxf(v.z, si1);
            a0 += fmaxf(v.w, si0); a1 += fmaxf(v.w, si1);
            a0 += fmaxf(u.x, si0); a1 += fmaxf(u.x, si1);
            a0 += fmaxf(u.y, si0); a1 += fmaxf(u.y, si1);
            a0 += fmaxf(u.z, si0); a1 += fmaxf(u.z, si1);
            a0 += fmaxf(u.w, si0); a1 += fmaxf(u.w, si1);
        }
        if (jj < jend) {
            const float4 v = neg4[jj];
            a0 += fmaxf(v.x, si0); a1 += fmaxf(v.x, si1);
            a0 += fmaxf(v.y, si0); a1 += fmaxf(v.y, si1);
            a0 += fmaxf(v.z, si0); a1 += fmaxf(v.z, si1);
            a0 += fmaxf(v.w, si0); a1 += fmaxf(v.w, si1);
        }
        tot += (a0 - jcntf * si0) + (a1 - jcntf * si1);
        g += 2;
    }
    // 1-group sweep.
    if (g < ngroups) {
        const float si0 = pos_s[(g << 6) + lane];
        float a0 = 0.f, a1 = 0.f;
        int jj = jbeg;
        for (; jj + 1 < jend; jj += 2) {
            const float4 v = neg4[jj];
            const float4 u = neg4[jj + 1];
            a0 += fmaxf(v.x, si0); a1 += fmaxf(v.y, si0);
            a0 += fmaxf(v.z, si0); a1 += fmaxf(v.w, si0);
            a0 += fmaxf(u.x, si0); a1 += fmaxf(u.y, si0);
            a0 += fmaxf(u.z, si0); a1 += fmaxf(u.w, si0);
        }
        if (jj < jend) {
            const float4 v = neg4[jj];
            a0 += fmaxf(v.x, si0); a1 += fmaxf(v.y, si0);
            a0 += fmaxf(v.z, si0); a1 += fmaxf(v.w, si0);
        }
        tot += (a0 + a1) - jcntf * si0;
    }

    for (int off = 32; off > 0; off >>= 1) tot += __shfl_down(tot, off, 64);
    if (lane == 0) red[wave] = tot;
    __syncthreads();

    if (tid == 0) {
        const float t = red[0] + red[1] + red[2] + red[3];
        const float cnt = (float)np * (float)nn;
        float2 r;
        r.x = (cnt > 0.f) ? t / cnt : 0.f;
        r.y = (cnt > 0.f) ? 1.f : 0.f;
        ws[b] = r;
    }
}

__global__ __launch_bounds__(BLOCK) void rk_finalize(const float2* __restrict__ ws,
                                                     float* __restrict__ out) {
    __shared__ float2 red[BLOCK / 64];
    const int tid = threadIdx.x;
    const int lane = tid & 63;
    const int wave = tid >> 6;

    float sm = 0.f, sv = 0.f;
    for (int i = tid; i < NBLOCKS; i += BLOCK) {
        const float2 v = ws[i];
        sm += v.x;
        sv += v.y;
    }
    for (int off = 32; off > 0; off >>= 1) {
        sm += __shfl_down(sm, off, 64);
        sv += __shfl_down(sv, off, 64);
    }
    if (lane == 0) red[wave] = make_float2(sm, sv);
    __syncthreads();

    if (tid == 0) {
        float tm = 0.f, tv = 0.f;
        for (int w = 0; w < BLOCK / 64; ++w) { tm += red[w].x; tv += red[w].y; }
        out[0] = tm / tv;
    }
}

extern "C" void kernel_launch(void* const* d_in, const int* in_sizes, int n_in,
                              void* d_out, int out_size, void* d_ws, size_t ws_size,
                              hipStream_t stream) {
    const float* scores = (const float*)d_in[0];
    const int*   labels = (const int*)d_in[1];
    float* out = (float*)d_out;
    float2* ws = (float2*)d_ws;

    rk_main<<<NBLOCKS, BLOCK, 0, stream>>>(scores, labels, ws);
    rk_finalize<<<1, BLOCK, 0, stream>>>(ws, out);
}